// Round 1
// baseline (65.205 us; speedup 1.0000x reference)
//
#include <hip/hip_runtime.h>
#include <math.h>

#define NB 81
#define NW 140

__device__ __constant__ float TBL[6] = {0.f, 5.f, 50.f, 500.f, 5000.f, 100000.f};

__device__ __forceinline__ int imax(int a, int b) { return a > b ? a : b; }
__device__ __forceinline__ int imin(int a, int b) { return a < b ? a : b; }

__device__ __forceinline__ float wave_sum(float v) {
#pragma unroll
    for (int m = 1; m < 64; m <<= 1) v += __shfl_xor(v, m, 64);
    return v;
}
__device__ __forceinline__ float wave_max(float v) {
#pragma unroll
    for (int m = 1; m < 64; m <<= 1) v = fmaxf(v, __shfl_xor(v, m, 64));
    return v;
}

// Unscaled logit for cell a (before the *0.03 softmax temperature).
__device__ __forceinline__ float cell_logit(int a, const int* bd, const unsigned* pw, float ev) {
    if (bd[a] != 0) return -1000000.0f;
    const int r = a / 9, c = a - 9 * (a / 9);
    float delta = 0.f;
    bool win = false;
    auto acc = [&](int w) {
        const unsigned v = pw[w];
        const int pc = (int)(v & 0xffu);
        const int oc = (int)(v >> 8);
        win |= (pc == 4);
        int pcn = pc + 1; if (pcn > 5) pcn = 5;   // jnp gather clamp; masked anyway
        if (oc == 0)      delta += TBL[pcn] - TBL[pc];  // TBL[0]==0 covers pc>0 guard
        else if (pc == 0) delta += TBL[oc];             // minus term vanishes for member windows
    };
    int lo, hi;
    // dir (0,1): id = r*5 + c0
    lo = imax(0, c - 4); hi = imin(c, 4);
    for (int c0 = lo; c0 <= hi; ++c0) acc(r * 5 + c0);
    // dir (1,0): id = 45 + r0*9 + c
    lo = imax(0, r - 4); hi = imin(r, 4);
    for (int r0 = lo; r0 <= hi; ++r0) acc(45 + r0 * 9 + c);
    // dir (1,1): id = 90 + (r-k)*5 + (c-k)
    lo = imax(0, imax(r - 4, c - 4)); hi = imin(4, imin(r, c));
    for (int k = lo; k <= hi; ++k) acc(90 + (r - k) * 5 + (c - k));
    // dir (1,-1): id = 115 + (r-k)*5 + (c+k-4), start col in [4,8]
    lo = imax(0, imax(r - 4, 4 - c)); hi = imin(4, imin(r, 8 - c));
    for (int k = lo; k <= hi; ++k) acc(115 + (r - k) * 5 + (c + k - 4));
    return win ? 100000.0f : (ev + delta);
}

__global__ __launch_bounds__(256) void heur9_kernel(const float* __restrict__ boards,
                                                    const int* __restrict__ cur,
                                                    float* __restrict__ out, int B) {
    __shared__ int sb[4][NB];
    __shared__ unsigned spw[4][NW];
    const int wave = threadIdx.x >> 6;
    const int lane = threadIdx.x & 63;
    const int b = (blockIdx.x << 2) | wave;   // grid = B/4 exactly (B=2048)

    int* bd = sb[wave];
    unsigned* pw = spw[wave];
    const float* brd = boards + b * NB;

    // Stage board into LDS as small ints (values are exactly 0/1/2).
    bd[lane] = (int)brd[lane];
    if (lane < NB - 64) bd[lane + 64] = (int)brd[lane + 64];
    const int player = cur[b];
    const int opp = 3 - player;
    __syncthreads();

    // Window pass: pc/oc per window, partial ev.
    float evp = 0.f;
    for (int w = lane; w < NW; w += 64) {
        int base, stride;
        if (w < 45)       { const int r = w / 5;        base = r * 9 + (w - r * 5);              stride = 1;  }
        else if (w < 90)  { const int t = w - 45, r0 = t / 9;  base = r0 * 9 + (t - r0 * 9);     stride = 9;  }
        else if (w < 115) { const int t = w - 90, r0 = t / 5;  base = r0 * 9 + (t - r0 * 5);     stride = 10; }
        else              { const int t = w - 115, r0 = t / 5; base = r0 * 9 + (t - r0 * 5) + 4; stride = 8;  }
        int pc = 0, oc = 0;
#pragma unroll
        for (int k = 0; k < 5; ++k) {
            const int v = bd[base + k * stride];
            pc += (v == player);
            oc += (v == opp);
        }
        pw[w] = (unsigned)(pc | (oc << 8));
        if (oc == 0)      evp += TBL[pc];   // TBL[0]==0 covers pc>0 guard
        else if (pc == 0) evp -= TBL[oc];
    }
    const float ev = wave_sum(evp);
    __syncthreads();

    // Cell pass: lane handles cell `lane` and (if lane<17) cell lane+64.
    const float l1 = cell_logit(lane, bd, pw, ev) * 0.03f;
    const float l2 = (lane < NB - 64) ? cell_logit(lane + 64, bd, pw, ev) * 0.03f : -INFINITY;

    const float m = wave_max(fmaxf(l1, l2));
    const float e1 = __expf(l1 - m);
    const float e2 = (lane < NB - 64) ? __expf(l2 - m) : 0.f;
    const float inv = 1.0f / wave_sum(e1 + e2);

    out[b * NB + lane] = e1 * inv;
    if (lane < NB - 64) out[b * NB + lane + 64] = e2 * inv;
    if (lane == 0) {
        const float v = tanhf(ev * (1.f / 3000.f));
        out[B * NB + b] = fminf(fmaxf(v, -0.95f), 0.95f);
    }
}

extern "C" void kernel_launch(void* const* d_in, const int* in_sizes, int n_in,
                              void* d_out, int out_size, void* d_ws, size_t ws_size,
                              hipStream_t stream) {
    const float* boards = (const float*)d_in[0];
    const int* cur = (const int*)d_in[1];
    float* out = (float*)d_out;
    const int B = in_sizes[0] / NB;          // 2048
    const int blocks = B / 4;                // 512 blocks, 4 boards (waves) per block
    heur9_kernel<<<blocks, 256, 0, stream>>>(boards, cur, out, B);
}

// Round 2
// 57.754 us; speedup vs baseline: 1.1290x; 1.1290x over previous
//
#include <hip/hip_runtime.h>
#include <math.h>

#define NB 81
#define NW 140

struct Tables {
    unsigned long long mlo[NW];   // window membership mask, cells 0..63
    unsigned long long mhi[NW];   // cells 64..80
    unsigned cw32[NB][5];         // per-cell window ids, 4 u8 per u32, pad=140
};

constexpr Tables make_tables() {
    Tables t{};
    for (int a = 0; a < NB; ++a)
        for (int j = 0; j < 5; ++j) t.cw32[a][j] = 0x8C8C8C8Cu;  // 140 = dummy window (delta 0)
    int cnt[NB] = {};
    const int DR[4] = {0, 1, 1, 1};
    const int DC[4] = {1, 0, 1, -1};
    int w = 0;
    for (int d = 0; d < 4; ++d)
        for (int r = 0; r < 9; ++r)
            for (int c = 0; c < 9; ++c) {
                const int er = r + 4 * DR[d], ec = c + 4 * DC[d];
                if (er < 0 || er > 8 || ec < 0 || ec > 8) continue;
                unsigned long long lo = 0, hi = 0;
                for (int k = 0; k < 5; ++k) {
                    const int cell = (r + k * DR[d]) * 9 + (c + k * DC[d]);
                    if (cell < 64) lo |= 1ull << cell;
                    else           hi |= 1ull << (cell - 64);
                    const int i = cnt[cell]++;
                    t.cw32[cell][i >> 2] &= ~(0xFFu << (8 * (i & 3)));
                    t.cw32[cell][i >> 2] |= (unsigned)w << (8 * (i & 3));
                }
                t.mlo[w] = lo; t.mhi[w] = hi; ++w;
            }
    return t;
}

__device__ __constant__ Tables TAB = make_tables();
__device__ __constant__ float PT[6] = {0.f, 5.f, 50.f, 500.f, 5000.f, 100000.f};
// DT[pc] = T[pc+1]-T[pc]; DT[5] unused (full windows touch only occupied cells)
__device__ __constant__ float DT[6] = {5.f, 45.f, 450.f, 4500.f, 95000.f, 0.f};

__device__ __forceinline__ float wave_sum(float v) {
#pragma unroll
    for (int m = 1; m < 64; m <<= 1) v += __shfl_xor(v, m, 64);
    return v;
}
__device__ __forceinline__ float wave_max(float v) {
#pragma unroll
    for (int m = 1; m < 64; m <<= 1) v = fmaxf(v, __shfl_xor(v, m, 64));
    return v;
}

__global__ __launch_bounds__(256) void heur9_kernel(const float* __restrict__ boards,
                                                    const int* __restrict__ cur,
                                                    float* __restrict__ out, int B) {
    __shared__ float sD[4][NW + 1];
    const int wave = threadIdx.x >> 6;
    const int lane = threadIdx.x & 63;
    const int b = (blockIdx.x << 2) | wave;   // grid = B/4 exactly
    float* dl = sD[wave];
    const float* brd = boards + b * NB;

    const float pf = (float)cur[b];
    const float of = 3.0f - pf;
    const float v1 = brd[lane];
    const float v2 = (lane < NB - 64) ? brd[lane + 64] : -1.0f;

    // Occupancy bitboards via wave ballot (uniform across wave).
    const unsigned long long p_lo = __ballot(v1 == pf);
    const unsigned long long p_hi = __ballot((lane < NB - 64) && v2 == pf);
    const unsigned long long o_lo = __ballot(v1 == of);
    const unsigned long long o_hi = __ballot((lane < NB - 64) && v2 == of);
    const unsigned long long e_lo = ~(p_lo | o_lo);
    const unsigned long long e_hi = ~(p_hi | o_hi);  // only low 17 bits meaningful

    // Window pass: per-window delta (shared by all member cells) + ev partial.
    float evp = 0.f;
    for (int w = lane; w < NW; w += 64) {
        const int pc = __popcll(p_lo & TAB.mlo[w]) + __popcll(p_hi & TAB.mhi[w]);
        const int oc = __popcll(o_lo & TAB.mlo[w]) + __popcll(o_hi & TAB.mhi[w]);
        float d = 0.f;
        if (oc == 0)      { d = DT[pc]; evp += PT[pc]; }   // PT[0]==0 covers pc>0 guard
        else if (pc == 0) { d = PT[oc]; evp -= PT[oc]; }
        if (pc == 4) d = 1.0e9f;  // win marker; empty-cell non-win sum < 1e5 << 5e8
        dl[w] = d;
    }
    if (lane == 0) dl[NW] = 0.f;  // dummy window for table padding
    const float ev = wave_sum(evp);
    __syncthreads();

    // Cell pass: gather <=20 per-window deltas via constexpr index table.
    float sd1 = 0.f, sd2 = 0.f;
#pragma unroll
    for (int j = 0; j < 5; ++j) {
        const unsigned q = TAB.cw32[lane][j];
        sd1 += dl[q & 255] + dl[(q >> 8) & 255] + dl[(q >> 16) & 255] + dl[q >> 24];
    }
    if (lane < NB - 64) {
#pragma unroll
        for (int j = 0; j < 5; ++j) {
            const unsigned q = TAB.cw32[lane + 64][j];
            sd2 += dl[q & 255] + dl[(q >> 8) & 255] + dl[(q >> 16) & 255] + dl[q >> 24];
        }
    }
    const bool emp1 = (e_lo >> lane) & 1ull;
    const bool emp2 = (lane < NB - 64) && ((e_hi >> lane) & 1ull);
    float l1 = emp1 ? (sd1 >= 5.0e8f ? 100000.f : ev + sd1) : -1000000.f;
    float l2 = (lane < NB - 64)
                 ? (emp2 ? (sd2 >= 5.0e8f ? 100000.f : ev + sd2) : -1000000.f)
                 : -INFINITY;
    l1 *= 0.03f; l2 *= 0.03f;

    const float m = wave_max(fmaxf(l1, l2));
    const float e1 = __expf(l1 - m);
    const float e2 = (lane < NB - 64) ? __expf(l2 - m) : 0.f;
    const float inv = 1.0f / wave_sum(e1 + e2);

    out[b * NB + lane] = e1 * inv;
    if (lane < NB - 64) out[b * NB + lane + 64] = e2 * inv;
    if (lane == 0) {
        const float v = tanhf(ev * (1.f / 3000.f));
        out[B * NB + b] = fminf(fmaxf(v, -0.95f), 0.95f);
    }
}

extern "C" void kernel_launch(void* const* d_in, const int* in_sizes, int n_in,
                              void* d_out, int out_size, void* d_ws, size_t ws_size,
                              hipStream_t stream) {
    const float* boards = (const float*)d_in[0];
    const int* cur = (const int*)d_in[1];
    float* out = (float*)d_out;
    const int B = in_sizes[0] / NB;   // 2048
    heur9_kernel<<<B / 4, 256, 0, stream>>>(boards, cur, out, B);
}